// Round 3
// baseline (273.813 us; speedup 1.0000x reference)
//
#include <hip/hip_runtime.h>

// ---------------------------------------------------------------------------
// sLSTM cell, B=8192, D=1024, H=1024.
//   pre[B,4H] = [x,h_prev] @ [Wg|Rg]^T  (K = D+H = 2048)
//   i=exp(pi+bi), f=sig(pf+bf), o=sig(po+bo), z=tanh(pz+bz)
//   c=f*c_prev+i*z ; n=f*n_prev+i ; m=max(log f + m_prev, pi) ; h=o*c/n
//   outputs (flat): h, c, C_prev(copy), n, m  -- each B*H f32
//
// Round 3: deep-pipelined GEMM (T3+T4+T5).
//   BM=256 BN=128 BK=64, 8 waves (4Mx2N), per-wave 64x64, acc[4][4].
//   Ring-3 LDS slots (144KB). During tile t, prefetch tile t+2 into the slot
//   vacated by tile t-1 (its reads drained before this tile's barrier ->
//   async LDS-write landing is race-free). One counted s_waitcnt vmcnt(6) +
//   one raw s_barrier per K-tile; never vmcnt(0) in the steady-state loop.
//   setprio(1) around each 16-MFMA cluster. Fused lane-local sLSTM epilogue
//   (gate-interleaved W packing: packed row r -> gate (r>>4)&3,
//   j=(r>>6)*16+(r&15)). C_prev passthrough via hipMemcpyAsync.
// ---------------------------------------------------------------------------

#define B_SZ 8192
#define D_SZ 1024
#define H_SZ 1024
#define K_SZ 2048   // D + H
#define N4H  4096   // 4*H
#define NT   32     // K_SZ / 64 K-tiles

typedef __attribute__((ext_vector_type(4))) float f32x4;
typedef _Float16 f16;
typedef __attribute__((ext_vector_type(8))) f16 f16x8;
typedef unsigned short u16;
typedef __attribute__((ext_vector_type(4))) unsigned short u16x4;

static __device__ __forceinline__ u16 f2h(float f) {
    f16 h = (f16)f;
    return __builtin_bit_cast(unsigned short, h);
}

static __device__ __forceinline__ void load_lds16(const void* g, void* l) {
    __builtin_amdgcn_global_load_lds(
        (const __attribute__((address_space(1))) void*)g,
        (__attribute__((address_space(3))) void*)l, 16, 0, 0);
}

// ---------------------------------------------------------------------------
// Pack A[B][K] = [x | h_prev] as fp16
// ---------------------------------------------------------------------------
__global__ void convert_A(const float* __restrict__ x, const float* __restrict__ h,
                          u16* __restrict__ A) {
    const size_t nvec = (size_t)B_SZ * K_SZ / 4;
    const size_t stride = (size_t)gridDim.x * blockDim.x;
    for (size_t v = (size_t)blockIdx.x * blockDim.x + threadIdx.x; v < nvec; v += stride) {
        size_t e = v * 4;
        size_t row = e >> 11;
        int col = (int)(e & 2047);
        const float* src = (col < D_SZ) ? (x + row * D_SZ + col)
                                        : (h + row * H_SZ + (col - D_SZ));
        f32x4 val = *(const f32x4*)src;
        u16x4 o;
        o[0] = f2h(val[0]); o[1] = f2h(val[1]); o[2] = f2h(val[2]); o[3] = f2h(val[3]);
        *(u16x4*)(A + e) = o;
    }
}

// ---------------------------------------------------------------------------
// Pack W[4H][K] gate-interleaved: packed row r -> gate g=(r>>4)&3,
// j = (r>>6)*16 + (r&15); content = [Wg[j,:] | Rg[j,:]] as fp16.
// ---------------------------------------------------------------------------
__global__ void convert_W(const float* __restrict__ Wi, const float* __restrict__ Wf,
                          const float* __restrict__ Wo, const float* __restrict__ Wz,
                          const float* __restrict__ Ri, const float* __restrict__ Rf,
                          const float* __restrict__ Ro, const float* __restrict__ Rz,
                          u16* __restrict__ Wb) {
    const size_t nvec = (size_t)N4H * K_SZ / 4;
    const size_t stride = (size_t)gridDim.x * blockDim.x;
    for (size_t v = (size_t)blockIdx.x * blockDim.x + threadIdx.x; v < nvec; v += stride) {
        size_t e = v * 4;
        size_t r = e >> 11;                 // packed row 0..4095
        int col = (int)(e & 2047);
        int g = (int)(r >> 4) & 3;          // gate
        int j = (int)((r >> 6) << 4) | (int)(r & 15);
        const float* Wg = (g == 0) ? Wi : (g == 1) ? Wf : (g == 2) ? Wo : Wz;
        const float* Rg = (g == 0) ? Ri : (g == 1) ? Rf : (g == 2) ? Ro : Rz;
        const float* src = (col < D_SZ) ? (Wg + (size_t)j * D_SZ + col)
                                        : (Rg + (size_t)j * H_SZ + (col - D_SZ));
        f32x4 val = *(const f32x4*)src;
        u16x4 o;
        o[0] = f2h(val[0]); o[1] = f2h(val[1]); o[2] = f2h(val[2]); o[3] = f2h(val[3]);
        *(u16x4*)(Wb + e) = o;
    }
}

// ---------------------------------------------------------------------------
// Deep-pipelined fused GEMM + sLSTM epilogue. 512 threads.
// ---------------------------------------------------------------------------
__global__ __launch_bounds__(512, 2)
void gemm_fused(const u16* __restrict__ A, const u16* __restrict__ W,
                const float* __restrict__ c_prev, const float* __restrict__ n_prev,
                const float* __restrict__ m_prev,
                const float* __restrict__ bi, const float* __restrict__ bfv,
                const float* __restrict__ bo, const float* __restrict__ bz,
                float* __restrict__ out) {
    __shared__ u16 lA[3][256 * 64];   // 3 x 32KB = 96KB
    __shared__ u16 lB[3][128 * 64];   // 3 x 16KB = 48KB

    const int tid = threadIdx.x;
    const int w   = tid >> 6;          // wave 0..7
    const int l   = tid & 63;
    const int wmm = w >> 1;            // M-wave 0..3 (64 rows each)
    const int wn  = w & 1;             // N-wave 0..1 (64 cols each)

    // XCD-aware bijective swizzle; grid = 1024 = 32 bm x 32 bn, nwg%8==0.
    // Per XCD: 4 consecutive bn panels x all bm (B panel L2-resident).
    const int xcd = blockIdx.x & 7;
    const int loc = blockIdx.x >> 3;       // 0..127
    const int bm  = loc & 31;
    const int bn  = xcd * 4 + (loc >> 5);  // 0..31
    const int m0  = bm * 256;
    const int n0r = bn * 128;              // packed-W row base

    // staging geometry: per gload issue, wave w covers 8 rows (1KB LDS, linear)
    const int lrow8 = l >> 3;              // 0..7
    const int lcol  = l & 7;               // 16B segment within row
    const int srow  = w * 8 + lrow8;       // 0..63 (row within 64-row chunk)
    const int gsegoff = (lcol ^ lrow8) * 8;  // pre-swizzled global seg offset (u16)

    // per-lane global src base pointers (advance by kt*64 per call)
    const u16* pA[4];
#pragma unroll
    for (int q = 0; q < 4; ++q)
        pA[q] = A + (size_t)(m0 + q * 64 + srow) * K_SZ + gsegoff;
    const u16* pB[2];
#pragma unroll
    for (int q = 0; q < 2; ++q)
        pB[q] = W + (size_t)(n0r + q * 64 + srow) * K_SZ + gsegoff;

    const int fr = l & 15;   // fragment row / C col
    const int kq = l >> 4;   // k-quad 0..3

    f32x4 acc[4][4] = {};

    auto stage_a = [&](int q, int kt, int slot) {
        load_lds16(pA[q] + kt * 64,
                   (char*)&lA[slot][0] + (q * 64 + w * 8) * 128);
    };
    auto stage_b = [&](int q, int kt, int slot) {
        load_lds16(pB[q] + kt * 64,
                   (char*)&lB[slot][0] + (q * 64 + w * 8) * 128);
    };

    auto do_phase = [&](int slot, int ks) {
        f16x8 af[4], bfr[4];
#pragma unroll
        for (int mi = 0; mi < 4; ++mi) {
            int row = wmm * 64 + mi * 16 + fr;                 // 0..255
            int seg = (ks * 4 + kq) ^ (row & 7);
            af[mi] = *(const f16x8*)&lA[slot][row * 64 + seg * 8];
        }
#pragma unroll
        for (int ni = 0; ni < 4; ++ni) {
            int row = wn * 64 + ni * 16 + fr;                  // 0..127
            int seg = (ks * 4 + kq) ^ (row & 7);
            bfr[ni] = *(const f16x8*)&lB[slot][row * 64 + seg * 8];
        }
        __builtin_amdgcn_s_setprio(1);
#pragma unroll
        for (int mi = 0; mi < 4; ++mi)
#pragma unroll
            for (int ni = 0; ni < 4; ++ni)
                acc[mi][ni] = __builtin_amdgcn_mfma_f32_16x16x32_f16(
                    af[mi], bfr[ni], acc[mi][ni], 0, 0, 0);
        __builtin_amdgcn_s_setprio(0);
    };

    // prologue: stage tiles 0,1 into slots 0,1 (12 issues/wave)
#pragma unroll
    for (int q = 0; q < 4; ++q) stage_a(q, 0, 0);
    stage_b(0, 0, 0); stage_b(1, 0, 0);
#pragma unroll
    for (int q = 0; q < 4; ++q) stage_a(q, 1, 1);
    stage_b(0, 1, 1); stage_b(1, 1, 1);

    // per-tile: counted wait (tile t done, t+1's 6 stay in flight), raw
    // barrier, then 2 phases; prefetch t+2 into slot((t+2)%3) = slot(t-1).
#define TILE_STEP(T, SC, SPF, PF, W6)                                        \
    do {                                                                     \
        if (W6) { asm volatile("s_waitcnt vmcnt(6)" ::: "memory"); }         \
        else    { asm volatile("s_waitcnt vmcnt(0)" ::: "memory"); }         \
        __builtin_amdgcn_s_barrier();                                        \
        if (PF) { stage_a(0, (T) + 2, (SPF)); stage_a(1, (T) + 2, (SPF));    \
                  stage_b(0, (T) + 2, (SPF)); }                              \
        do_phase((SC), 0);                                                   \
        if (PF) { stage_a(2, (T) + 2, (SPF)); stage_a(3, (T) + 2, (SPF));    \
                  stage_b(1, (T) + 2, (SPF)); }                              \
        do_phase((SC), 1);                                                   \
    } while (0)

#pragma unroll 1
    for (int t = 0; t < 30; t += 3) {
        TILE_STEP(t,     0, 2, true, true);
        TILE_STEP(t + 1, 1, 0, true, true);
        TILE_STEP(t + 2, 2, 1, true, true);
    }
    TILE_STEP(30, 0, 0, false, true);    // tile 31's 6 issues still in flight
    TILE_STEP(31, 1, 0, false, false);   // final drain
#undef TILE_STEP

    // ---- fused sLSTM epilogue (fully lane-local) -------------------------
    const size_t BH = (size_t)B_SZ * H_SZ;
    const int j = (bn * 2 + wn) * 16 + fr;            // 0..1023
    const float bvi = bi[j], bvf = bfv[j], bvo = bo[j], bvz = bz[j];

#pragma unroll
    for (int mi = 0; mi < 4; ++mi) {
        const int rbase = m0 + wmm * 64 + mi * 16 + kq * 4;
#pragma unroll
        for (int r2 = 0; r2 < 4; ++r2) {
            const size_t idx = (size_t)(rbase + r2) * H_SZ + j;
            float pi = acc[mi][0][r2] + bvi;
            float pf = acc[mi][1][r2] + bvf;
            float po = acc[mi][2][r2] + bvo;
            float pz = acc[mi][3][r2] + bvz;
            float iv = __expf(pi);
            float fv = 1.0f / (1.0f + __expf(-pf));
            float ov = 1.0f / (1.0f + __expf(-po));
            float e2 = __expf(2.0f * pz);
            float zv = 1.0f - 2.0f / (e2 + 1.0f);     // tanh(pz)
            float cv = fv * c_prev[idx] + iv * zv;
            float nv = fv * n_prev[idx] + iv;
            float mv = fmaxf(__logf(fv) + m_prev[idx], pi);
            out[idx]          = ov * (cv / nv);       // h
            out[BH + idx]     = cv;                   // c
            out[3 * BH + idx] = nv;                   // n
            out[4 * BH + idx] = mv;                   // m
        }
    }
}

// ---------------------------------------------------------------------------
extern "C" void kernel_launch(void* const* d_in, const int* in_sizes, int n_in,
                              void* d_out, int out_size, void* d_ws, size_t ws_size,
                              hipStream_t stream) {
    const float* x      = (const float*)d_in[0];
    const float* h_prev = (const float*)d_in[1];
    const float* c_prev = (const float*)d_in[2];
    const float* C_prev = (const float*)d_in[3];
    const float* n_prev = (const float*)d_in[4];
    const float* m_prev = (const float*)d_in[5];
    const float* Wz = (const float*)d_in[6];
    const float* bz = (const float*)d_in[7];
    const float* Rz = (const float*)d_in[8];
    const float* Wi = (const float*)d_in[9];
    const float* bi = (const float*)d_in[10];
    const float* Ri = (const float*)d_in[11];
    const float* Wf = (const float*)d_in[12];
    const float* bf = (const float*)d_in[13];
    const float* Rf = (const float*)d_in[14];
    const float* Wo = (const float*)d_in[15];
    const float* bo = (const float*)d_in[16];
    const float* Ro = (const float*)d_in[17];
    float* out = (float*)d_out;

    const size_t BH = (size_t)B_SZ * H_SZ;

    // workspace layout: A_f16 (32MB) | W_f16 (16MB)
    u16* Abuf = (u16*)d_ws;
    u16* Wbuf = (u16*)((char*)d_ws + (size_t)32 * 1024 * 1024);

    convert_A<<<2048, 256, 0, stream>>>(x, h_prev, Abuf);
    convert_W<<<2048, 256, 0, stream>>>(Wi, Wf, Wo, Wz, Ri, Rf, Ro, Rz, Wbuf);

    hipMemcpyAsync(out + 2 * BH, C_prev, BH * sizeof(float),
                   hipMemcpyDeviceToDevice, stream);

    gemm_fused<<<dim3((B_SZ / 256) * (N4H / 128)), 512, 0, stream>>>(
        Abuf, Wbuf, c_prev, n_prev, m_prev, bi, bf, bo, bz, out);
}

// Round 4
// 242.620 us; speedup vs baseline: 1.1286x; 1.1286x over previous
//
#include <hip/hip_runtime.h>

// ---------------------------------------------------------------------------
// sLSTM cell, B=8192, D=1024, H=1024.
//   pre[B,4H] = [x,h_prev] @ [Wg|Rg]^T  (K = D+H = 2048)
//   i=exp(pi+bi), f=sig(pf+bf), o=sig(po+bo), z=tanh(pz+bz)
//   c=f*c_prev+i*z ; n=f*n_prev+i ; m=max(log f + m_prev, pi) ; h=o*c/n
//   outputs (flat): h, c, C_prev(copy), n, m  -- each B*H f32
//
// Round 4: T4 isolation on the round-2 base. 128x128 tile, BK=64, 4 waves,
// ring-2 LDS (64KB -> 2 blocks/CU). Per K-tile: issue stage(t+1) into the
// other slot FIRST, then counted s_waitcnt vmcnt(8) (stage(t) landed, the 8
// new loads stay in flight), raw s_barrier, 2x16 MFMA, raw s_barrier. No
// vmcnt(0) drain until the last tile. Natural grid mapping (bm fastest =
// round-2's verified 205MB fetch). Fused lane-local sLSTM epilogue
// (gate-interleaved W packing). C_prev passthrough via hipMemcpyAsync.
// ---------------------------------------------------------------------------

#define B_SZ 8192
#define D_SZ 1024
#define H_SZ 1024
#define K_SZ 2048   // D + H
#define N4H  4096   // 4*H

typedef __attribute__((ext_vector_type(4))) float f32x4;
typedef _Float16 f16;
typedef __attribute__((ext_vector_type(8))) f16 f16x8;
typedef unsigned short u16;
typedef __attribute__((ext_vector_type(4))) unsigned short u16x4;

static __device__ __forceinline__ u16 f2h(float f) {
    f16 h = (f16)f;
    return __builtin_bit_cast(unsigned short, h);
}

static __device__ __forceinline__ void load_lds16(const void* g, void* l) {
    __builtin_amdgcn_global_load_lds(
        (const __attribute__((address_space(1))) void*)g,
        (__attribute__((address_space(3))) void*)l, 16, 0, 0);
}

// ---------------------------------------------------------------------------
// Pack A[B][K] = [x | h_prev] as fp16
// ---------------------------------------------------------------------------
__global__ void convert_A(const float* __restrict__ x, const float* __restrict__ h,
                          u16* __restrict__ A) {
    const size_t nvec = (size_t)B_SZ * K_SZ / 4;
    const size_t stride = (size_t)gridDim.x * blockDim.x;
    for (size_t v = (size_t)blockIdx.x * blockDim.x + threadIdx.x; v < nvec; v += stride) {
        size_t e = v * 4;
        size_t row = e >> 11;
        int col = (int)(e & 2047);
        const float* src = (col < D_SZ) ? (x + row * D_SZ + col)
                                        : (h + row * H_SZ + (col - D_SZ));
        f32x4 val = *(const f32x4*)src;
        u16x4 o;
        o[0] = f2h(val[0]); o[1] = f2h(val[1]); o[2] = f2h(val[2]); o[3] = f2h(val[3]);
        *(u16x4*)(A + e) = o;
    }
}

// ---------------------------------------------------------------------------
// Pack W[4H][K] gate-interleaved: packed row r -> gate g=(r>>4)&3,
// j = (r>>6)*16 + (r&15); content = [Wg[j,:] | Rg[j,:]] as fp16.
// ---------------------------------------------------------------------------
__global__ void convert_W(const float* __restrict__ Wi, const float* __restrict__ Wf,
                          const float* __restrict__ Wo, const float* __restrict__ Wz,
                          const float* __restrict__ Ri, const float* __restrict__ Rf,
                          const float* __restrict__ Ro, const float* __restrict__ Rz,
                          u16* __restrict__ Wb) {
    const size_t nvec = (size_t)N4H * K_SZ / 4;
    const size_t stride = (size_t)gridDim.x * blockDim.x;
    for (size_t v = (size_t)blockIdx.x * blockDim.x + threadIdx.x; v < nvec; v += stride) {
        size_t e = v * 4;
        size_t r = e >> 11;                 // packed row 0..4095
        int col = (int)(e & 2047);
        int g = (int)(r >> 4) & 3;          // gate
        int j = (int)((r >> 6) << 4) | (int)(r & 15);
        const float* Wg = (g == 0) ? Wi : (g == 1) ? Wf : (g == 2) ? Wo : Wz;
        const float* Rg = (g == 0) ? Ri : (g == 1) ? Rf : (g == 2) ? Ro : Rz;
        const float* src = (col < D_SZ) ? (Wg + (size_t)j * D_SZ + col)
                                        : (Rg + (size_t)j * H_SZ + (col - D_SZ));
        f32x4 val = *(const f32x4*)src;
        u16x4 o;
        o[0] = f2h(val[0]); o[1] = f2h(val[1]); o[2] = f2h(val[2]); o[3] = f2h(val[3]);
        *(u16x4*)(Wb + e) = o;
    }
}

// ---------------------------------------------------------------------------
// Fused GEMM + sLSTM epilogue, ring-2 counted-vmcnt pipeline. 256 threads.
// ---------------------------------------------------------------------------
__global__ __launch_bounds__(256, 2)
void gemm_fused(const u16* __restrict__ A, const u16* __restrict__ W,
                const float* __restrict__ c_prev, const float* __restrict__ n_prev,
                const float* __restrict__ m_prev,
                const float* __restrict__ bi, const float* __restrict__ bfv,
                const float* __restrict__ bo, const float* __restrict__ bz,
                float* __restrict__ out) {
    __shared__ u16 lA[2][128 * 64];   // 2 x 16KB
    __shared__ u16 lB[2][128 * 64];   // 2 x 16KB  (64KB total -> 2 blocks/CU)

    const int tid = threadIdx.x;
    const int w  = tid >> 6;       // wave 0..3
    const int l  = tid & 63;       // lane
    const int wm = w >> 1;         // wave row (2)
    const int wn = w & 1;          // wave col (2)
    const int m0 = blockIdx.x * 128;
    const int n0 = blockIdx.y * 128;

    const int lrow8 = l >> 3;            // row within the wave's 8-row stripe
    const int lseg  = (l & 7) ^ lrow8;   // pre-swizzled global 16B-segment index

    const int fr = l & 15;   // fragment row (M for A, N for B), also C col
    const int kq = l >> 4;   // k-quad 0..3

    f32x4 acc[4][4] = {};

    // 8 async issues per wave per tile
    auto stage = [&](int kt, int slot) {
#pragma unroll
        for (int r = 0; r < 4; ++r) {
            int rowA = r * 32 + w * 8 + lrow8;               // 0..127
            const u16* gA = A + (size_t)(m0 + rowA) * K_SZ + kt * 64 + lseg * 8;
            load_lds16(gA, (char*)&lA[slot][0] + (r * 32 + w * 8) * 128);
            const u16* gB = W + (size_t)(n0 + rowA) * K_SZ + kt * 64 + lseg * 8;
            load_lds16(gB, (char*)&lB[slot][0] + (r * 32 + w * 8) * 128);
        }
    };

    auto do_phase = [&](int slot, int ks) {
        f16x8 af[4], bfr[4];
#pragma unroll
        for (int mi = 0; mi < 4; ++mi) {
            int row = wm * 64 + mi * 16 + fr;
            int seg = (ks * 4 + kq) ^ (row & 7);
            af[mi] = *(const f16x8*)&lA[slot][row * 64 + seg * 8];
        }
#pragma unroll
        for (int ni = 0; ni < 4; ++ni) {
            int row = wn * 64 + ni * 16 + fr;
            int seg = (ks * 4 + kq) ^ (row & 7);
            bfr[ni] = *(const f16x8*)&lB[slot][row * 64 + seg * 8];
        }
        __builtin_amdgcn_s_setprio(1);
#pragma unroll
        for (int mi = 0; mi < 4; ++mi)
#pragma unroll
            for (int ni = 0; ni < 4; ++ni)
                acc[mi][ni] = __builtin_amdgcn_mfma_f32_16x16x32_f16(
                    af[mi], bfr[ni], acc[mi][ni], 0, 0, 0);
        __builtin_amdgcn_s_setprio(0);
    };

    // Ring-2 pipeline over 32 K-tiles; slots are compile-time (2 tiles/iter).
    // Ledger: stage(t+1 -> S^1) issues only after the end-of-iter barrier of
    // t-1 (all reads of S^1 done). Readers of S^1 cross a barrier that the
    // staging wave reaches only after its vmcnt(8) confirms stage(t) landed;
    // its stage(t+1) writes are confirmed by its vmcnt wait in the next iter.
    stage(0, 0);
#pragma unroll 1
    for (int t = 0; t < 32; t += 2) {
        // ---- tile t (slot 0) ----
        stage(t + 1, 1);                                   // t+1 <= 31 always
        asm volatile("s_waitcnt vmcnt(8)" ::: "memory");   // stage(t) landed
        __builtin_amdgcn_s_barrier();
        do_phase(0, 0);
        do_phase(0, 1);
        __builtin_amdgcn_s_barrier();                      // reads of slot0 done
        // ---- tile t+1 (slot 1) ----
        if (t + 2 < 32) {
            stage(t + 2, 0);
            asm volatile("s_waitcnt vmcnt(8)" ::: "memory");
        } else {
            asm volatile("s_waitcnt vmcnt(0)" ::: "memory");
        }
        __builtin_amdgcn_s_barrier();
        do_phase(1, 0);
        do_phase(1, 1);
        __builtin_amdgcn_s_barrier();
    }

    // ---- fused sLSTM epilogue (fully lane-local) -------------------------
    const size_t BH = (size_t)B_SZ * H_SZ;
    const int j = ((n0 + wn * 64) >> 6) * 16 + fr;    // 0..1023
    const float bvi = bi[j], bvf = bfv[j], bvo = bo[j], bvz = bz[j];

#pragma unroll
    for (int mi = 0; mi < 4; ++mi) {
        const int rbase = m0 + wm * 64 + mi * 16 + kq * 4;
#pragma unroll
        for (int r2 = 0; r2 < 4; ++r2) {
            const size_t idx = (size_t)(rbase + r2) * H_SZ + j;
            float pi = acc[mi][0][r2] + bvi;
            float pf = acc[mi][1][r2] + bvf;
            float po = acc[mi][2][r2] + bvo;
            float pz = acc[mi][3][r2] + bvz;
            float iv = __expf(pi);
            float fv = 1.0f / (1.0f + __expf(-pf));
            float ov = 1.0f / (1.0f + __expf(-po));
            float e2 = __expf(2.0f * pz);
            float zv = 1.0f - 2.0f / (e2 + 1.0f);     // tanh(pz)
            float cv = fv * c_prev[idx] + iv * zv;
            float nv = fv * n_prev[idx] + iv;
            float mv = fmaxf(__logf(fv) + m_prev[idx], pi);
            out[idx]          = ov * (cv / nv);       // h
            out[BH + idx]     = cv;                   // c
            out[3 * BH + idx] = nv;                   // n
            out[4 * BH + idx] = mv;                   // m
        }
    }
}

// ---------------------------------------------------------------------------
extern "C" void kernel_launch(void* const* d_in, const int* in_sizes, int n_in,
                              void* d_out, int out_size, void* d_ws, size_t ws_size,
                              hipStream_t stream) {
    const float* x      = (const float*)d_in[0];
    const float* h_prev = (const float*)d_in[1];
    const float* c_prev = (const float*)d_in[2];
    const float* C_prev = (const float*)d_in[3];
    const float* n_prev = (const float*)d_in[4];
    const float* m_prev = (const float*)d_in[5];
    const float* Wz = (const float*)d_in[6];
    const float* bz = (const float*)d_in[7];
    const float* Rz = (const float*)d_in[8];
    const float* Wi = (const float*)d_in[9];
    const float* bi = (const float*)d_in[10];
    const float* Ri = (const float*)d_in[11];
    const float* Wf = (const float*)d_in[12];
    const float* bf = (const float*)d_in[13];
    const float* Rf = (const float*)d_in[14];
    const float* Wo = (const float*)d_in[15];
    const float* bo = (const float*)d_in[16];
    const float* Ro = (const float*)d_in[17];
    float* out = (float*)d_out;

    const size_t BH = (size_t)B_SZ * H_SZ;

    // workspace layout: A_f16 (32MB) | W_f16 (16MB)
    u16* Abuf = (u16*)d_ws;
    u16* Wbuf = (u16*)((char*)d_ws + (size_t)32 * 1024 * 1024);

    convert_A<<<2048, 256, 0, stream>>>(x, h_prev, Abuf);
    convert_W<<<2048, 256, 0, stream>>>(Wi, Wf, Wo, Wz, Ri, Rf, Ro, Rz, Wbuf);

    hipMemcpyAsync(out + 2 * BH, C_prev, BH * sizeof(float),
                   hipMemcpyDeviceToDevice, stream);

    gemm_fused<<<dim3(B_SZ / 128, N4H / 128), 256, 0, stream>>>(
        Abuf, Wbuf, c_prev, n_prev, m_prev, bi, bf, bo, bz, out);
}